// Round 19
// baseline (251.190 us; speedup 1.0000x reference)
//
#include <hip/hip_runtime.h>
#include <hip/hip_bf16.h>

// ---------------------------------------------------------------------------
// myGRUCell low-rank, R19 = R18 with k1 testing the DRAM-contiguity theory:
//   k1 : A12 = [x@W | h@U] bf16.  R13 structure, chunk=128 f32 ->
//        staging segments 2-row x 512B (2x page payload), uniform per-iter
//        issue {16 ldg8 + 8 cp16} with VWAIT(24) = full next-chunk in flight.
//        LDS 64KB, grid 1024, 2 blocks/CU.
//   k23: rhU (R7/R14 col-split).           [unchanged]
//   k4 : gates+out (R8/R14 stationary-B).  [unchanged]
// ws layout (shorts): Wt[64][1024] | Ut | P1t[1024][128] | P2t | P3t |
//                     A12[32768][128] | rhU[32768][64]
// ---------------------------------------------------------------------------

typedef __attribute__((ext_vector_type(8))) short short8;
typedef __attribute__((ext_vector_type(4))) float f32x4;
typedef __attribute__((ext_vector_type(4))) float f4;

#define WS_UT   65536
#define WS_P1T  131072
#define WS_P2T  262144
#define WS_P3T  393216
#define WS_A12  524288
#define WS_RHU  4718592

__device__ __forceinline__ short f2bf(float f) {
  unsigned u = __builtin_bit_cast(unsigned, f);
  u += 0x7FFFu + ((u >> 16) & 1u);          // round-nearest-even
  return (short)(u >> 16);
}
__device__ __forceinline__ short8 cvt8(f4 a, f4 b) {
  short8 r;
#pragma unroll
  for (int j = 0; j < 4; ++j) { r[j] = f2bf(a[j]); r[4 + j] = f2bf(b[j]); }
  return r;
}
__device__ __forceinline__ f32x4 mfma16(short8 a, short8 b, f32x4 c) {
  return __builtin_amdgcn_mfma_f32_16x16x32_bf16(a, b, c, 0, 0, 0);
}
__device__ __forceinline__ short8 ldg8(const short* p) {
  return *reinterpret_cast<const short8*>(p);
}
__device__ __forceinline__ f4 ldf4(const float* p) {
  return *reinterpret_cast<const f4*>(p);
}

// async 16B global->LDS
__device__ __forceinline__ void cp16(void* l, const void* g) {
  __builtin_amdgcn_global_load_lds(
      (const __attribute__((address_space(1))) void*)g,
      (__attribute__((address_space(3))) void*)l, 16, 0, 0);
}
#define VWAIT(N) do { asm volatile("s_waitcnt vmcnt(" #N ")" ::: "memory"); \
                      __builtin_amdgcn_sched_barrier(0); } while (0)

// [R][128]-short LDS tile, XOR-swizzled 16B granules
__device__ __forceinline__ short8 rd128s(const short* b, int row, int col) {
  return *reinterpret_cast<const short8*>(b + row * 128 + (col ^ ((row & 7) << 3)));
}
__device__ __forceinline__ void wr128s(short* b, int row, int col8, short8 v) {
  *reinterpret_cast<short8*>(b + row * 128 + (col8 ^ ((row & 7) << 3))) = v;
}
// [16][64]-short per-wave transpose buffer
__device__ __forceinline__ void wr64(short* b, int row, int col, short v) {
  b[row * 64 + (col ^ ((row & 7) << 3))] = v;
}
__device__ __forceinline__ short8 rd64(const short* b, int row, int col) {
  return *reinterpret_cast<const short8*>(b + row * 64 + (col ^ ((row & 7) << 3)));
}

#define LOG2E 1.4426950408889634f
__device__ __forceinline__ float sigm_f(float v) {
  return __builtin_amdgcn_rcpf(1.f + __builtin_amdgcn_exp2f(-v * LOG2E));
}
__device__ __forceinline__ float tanh_f(float v) {
  float t = __builtin_amdgcn_exp2f(v * (2.f * LOG2E));
  return 1.f - 2.f * __builtin_amdgcn_rcpf(t + 1.f);
}

// ---------------------------------------------------------------------------
__global__ void prep_kernel(const float* __restrict__ W,  const float* __restrict__ W1,
                            const float* __restrict__ W2, const float* __restrict__ W3,
                            const float* __restrict__ U,  const float* __restrict__ U1,
                            const float* __restrict__ U2, const float* __restrict__ U3,
                            short* __restrict__ ws) {
  int i = blockIdx.x * blockDim.x + threadIdx.x;
  float v;
  if (i < 65536) {
    int n = i >> 10, k = i & 1023;
    v = W[k * 64 + n];
  } else if (i < 131072) {
    int j = i - 65536;
    int n = j >> 10, k = j & 1023;
    v = U[k * 64 + n];
  } else {
    int j = i - 131072;
    int sel = j >> 17;
    int jj = j & 131071;
    int n = jj >> 7, k = jj & 127;
    const float* Wk = sel == 0 ? W1 : sel == 1 ? W2 : W3;
    const float* Uk = sel == 0 ? U1 : sel == 1 ? U2 : U3;
    v = (k < 64) ? Wk[k * 1024 + n] : Uk[(k - 64) * 1024 + n];
  }
  ws[i] = f2bf(v);
}

// ---------------------------------------------------------------------------
// k1 (R19): A12 = [x@W | h@U].  Block 32 rows, 4 waves = (matrix m, row half).
// 8 chunks of 128 f32; staging = 8 cp16 of 2-row x 512B; weights reg-dbuf
// 16 ldg8/chunk; uniform issue + VWAIT(24).  grid 1024, 64 KB LDS.
// ---------------------------------------------------------------------------
__global__ __launch_bounds__(256, 2) void k1_a12(
    const float* __restrict__ x, const float* __restrict__ h,
    const short* __restrict__ ws, short* __restrict__ A12) {
  __shared__ __align__(16) float sS[2][4][16 * 128];   // [buf][wave][16r][128f]

  const int tid = threadIdx.x;
  const int w = tid >> 6, l = tid & 63, l15 = l & 15, lg = l >> 4;
  const int m = w >> 1, half = w & 1;
  const int sr = blockIdx.x * 32 + half * 16;
  const float* src = m ? h : x;
  const short* Bt  = ws + m * WS_UT;

  const int srow = l >> 5;            // 0..1: row within 2-row issue
  const int slin = (l & 31) * 16;     // byte within 512B row segment

  auto STAGE = [&](int c, int b) {
#pragma unroll
    for (int i = 0; i < 8; ++i) {
      int r = i * 2 + srow;
      int kb = slin ^ ((r & 7) << 4);  // pre-swizzled source (rule 21)
      cp16((char*)&sS[b][w][0] + i * 1024,
           (const char*)(src + (size_t)(sr + r) * 1024 + c * 128) + kb);
    }
  };
  auto WLOAD = [&](int c, short8* bw) {
#pragma unroll
    for (int ks = 0; ks < 4; ++ks)
#pragma unroll
      for (int cf = 0; cf < 4; ++cf)
        bw[ks * 4 + cf] =
            ldg8(Bt + (size_t)(cf * 16 + l15) * 1024 + c * 128 + ks * 32 + lg * 8);
  };

  f32x4 acc[4] = {};
  short8 bwb[2][16];
  STAGE(0, 0);
  WLOAD(0, bwb[0]);
#pragma unroll
  for (int c = 0; c < 8; ++c) {
    if (c < 7) {
      WLOAD(c + 1, bwb[(c + 1) & 1]);   // 16 ldg8
      STAGE(c + 1, (c + 1) & 1);        // 8 cp16
      VWAIT(24);                        // retire chunk c's 24; keep c+1 in flight
    } else {
      VWAIT(0);
    }
    const char* Bb = (const char*)&sS[c & 1][w][0];
    const int s = (l15 & 7) << 4;
    const short8* bw = bwb[c & 1];
#pragma unroll
    for (int ks = 0; ks < 4; ++ks) {
      const int kb0 = (ks * 32 + lg * 8) * 4;
      f4 pa = *(const f4*)(Bb + l15 * 512 + (kb0 ^ s));
      f4 pb = *(const f4*)(Bb + l15 * 512 + ((kb0 + 16) ^ s));
      short8 av = cvt8(pa, pb);
#pragma unroll
      for (int cf = 0; cf < 4; ++cf) acc[cf] = mfma16(av, bw[ks * 4 + cf], acc[cf]);
    }
  }
#pragma unroll
  for (int cf = 0; cf < 4; ++cf)
#pragma unroll
    for (int j = 0; j < 4; ++j)
      A12[(size_t)(sr + lg * 4 + j) * 128 + m * 64 + cf * 16 + l15] = f2bf(acc[cf][j]);
}

// ---------------------------------------------------------------------------
// k23 (R7/R14, unchanged): rhU = (sigmoid(A12@P1 + h*U1d + bR) * h) @ U.
// ---------------------------------------------------------------------------
__global__ __launch_bounds__(256, 4) void k23_rhu(
    const float* __restrict__ h, const float* __restrict__ u1d,
    const float* __restrict__ biasR,
    const short* __restrict__ ws, const short* __restrict__ A12,
    short* __restrict__ rhU) {
  const short* Ut  = ws + WS_UT;
  const short* P1t = ws + WS_P1T;
  __shared__ __align__(16) short sT[4][2][16 * 64];
  __shared__ __align__(16) float sRed[2][2][16 * 64];

  const int tid = threadIdx.x;
  const int w   = tid >> 6, l = tid & 63, l15 = l & 15, lg = l >> 4;
  const int s   = w >> 1;
  const int ch  = w & 1;
  const int sr  = blockIdx.x * 32 + s * 16;

  short8 a12[4];
#pragma unroll
  for (int k0 = 0; k0 < 4; ++k0)
    a12[k0] = ldg8(A12 + (size_t)(sr + l15) * 128 + k0 * 32 + lg * 8);

  f32x4 accU[4] = {};
#pragma unroll 1
  for (int tt = 0; tt < 8; ++tt) {
    const int n0 = ch * 512 + tt * 64;

    float hv[4][4];
#pragma unroll
    for (int cf = 0; cf < 4; ++cf)
#pragma unroll
      for (int j = 0; j < 4; ++j)
        hv[cf][j] = h[(size_t)(sr + lg * 4 + j) * 1024 + n0 + cf * 16 + l15];

    f32x4 accR[4] = {};
#pragma unroll
    for (int k0 = 0; k0 < 4; ++k0)
#pragma unroll
      for (int cf = 0; cf < 4; ++cf)
        accR[cf] = mfma16(a12[k0],
            ldg8(P1t + (size_t)(n0 + cf * 16 + l15) * 128 + k0 * 32 + lg * 8),
            accR[cf]);

    short* sw = &sT[w][tt & 1][0];
#pragma unroll
    for (int cf = 0; cf < 4; ++cf) {
      const int cc = n0 + cf * 16 + l15;
      const float d1 = u1d[cc], b_r = biasR[cc];
#pragma unroll
      for (int j = 0; j < 4; ++j) {
        float rv = sigm_f(accR[cf][j] + hv[cf][j] * d1 + b_r);
        wr64(sw, lg * 4 + j, cf * 16 + l15, f2bf(rv * hv[cf][j]));
      }
    }
    // wave-coherent RAW through LDS (lgkmcnt only; R5-R18 proven)
    short8 arh0 = rd64(sw, l15, lg * 8);
    short8 arh1 = rd64(sw, l15, 32 + lg * 8);
#pragma unroll
    for (int cf = 0; cf < 4; ++cf)
      accU[cf] = mfma16(arh0,
          ldg8(Ut + (size_t)(cf * 16 + l15) * 1024 + n0 + lg * 8), accU[cf]);
#pragma unroll
    for (int cf = 0; cf < 4; ++cf)
      accU[cf] = mfma16(arh1,
          ldg8(Ut + (size_t)(cf * 16 + l15) * 1024 + n0 + 32 + lg * 8), accU[cf]);
  }

  {
    float* fT = &sRed[s][ch][0];
#pragma unroll
    for (int cf = 0; cf < 4; ++cf)
#pragma unroll
      for (int j = 0; j < 4; ++j) {
        int row = lg * 4 + j, col = cf * 16 + l15;
        fT[row * 64 + (col ^ ((row & 7) << 2))] = accU[cf][j];
      }
  }
  __syncthreads();
  if (ch == 0) {
    const float* f0 = &sRed[s][0][0];
    const float* f1 = &sRed[s][1][0];
#pragma unroll
    for (int cf = 0; cf < 4; ++cf)
#pragma unroll
      for (int j = 0; j < 4; ++j) {
        int row = lg * 4 + j, col = cf * 16 + l15;
        int idx = row * 64 + (col ^ ((row & 7) << 2));
        rhU[(size_t)(sr + row) * 64 + col] = f2bf(f0[idx] + f1[idx]);
      }
  }
}

// ---------------------------------------------------------------------------
// k4 (R8/R14, unchanged): out = z*h + (1-z)*tanh(pre_c).
// ---------------------------------------------------------------------------
__global__ __launch_bounds__(256, 2) void k4_out(
    const float* __restrict__ h,
    const float* __restrict__ u1d, const float* __restrict__ u2d,
    const float* __restrict__ u3d,
    const float* __restrict__ biasR, const float* __restrict__ biasZ,
    const float* __restrict__ biasU,
    const short* __restrict__ ws, const short* __restrict__ A12,
    const short* __restrict__ rhU, float* __restrict__ out) {
  __shared__ __align__(16) short sB1[64 * 128], sB2[64 * 128], sB3[64 * 128];
  __shared__ __align__(16) float hS[2][4][16 * 64];

  const int tid = threadIdx.x;
  const int w = tid >> 6, l = tid & 63, l15 = l & 15, lg = l >> 4;
  const int ct = blockIdx.x & 15, rc = blockIdx.x >> 4;
  const int n0 = ct * 64;

#pragma unroll
  for (int mat = 0; mat < 3; ++mat) {
    const short* srcw = (mat == 0) ? (ws + WS_P1T) : (mat == 1) ? (ws + WS_P2T) : (ws + WS_P3T);
    short* dst = (mat == 0) ? sB1 : (mat == 1) ? sB2 : sB3;
#pragma unroll
    for (int i = 0; i < 4; ++i) {
      int id = tid + i * 256;
      int row = id >> 4, gc = id & 15;
      wr128s(dst, row, gc * 8, ldg8(srcw + (size_t)(n0 + row) * 128 + gc * 8));
    }
  }
  float d1_[4], d2_[4], d3_[4], br_[4], bz_[4], bu_[4];
#pragma unroll
  for (int cf = 0; cf < 4; ++cf) {
    const int cc = n0 + cf * 16 + l15;
    d1_[cf] = u1d[cc]; d2_[cf] = u2d[cc]; d3_[cf] = u3d[cc];
    br_[cf] = biasR[cc]; bz_[cf] = biasZ[cc]; bu_[cf] = biasU[cc];
  }
  __syncthreads();

  const int srow = l >> 4;
  const int slin = (l & 15) * 16;
  auto STAGE = [&](int rnd, int b) {
    const int sb = rc * 512 + rnd * 64 + w * 16;
#pragma unroll
    for (int i = 0; i < 4; ++i) {
      int r = i * 4 + srow;
      int kb = slin ^ ((r & 7) << 4);
      cp16((char*)&hS[b][w][0] + i * 1024,
           (const char*)(h + (size_t)(sb + r) * 1024 + n0) + kb);
    }
  };

  STAGE(0, 0);
#pragma unroll 1
  for (int rnd = 0; rnd < 8; ++rnd) {
    const int sr = rc * 512 + rnd * 64 + w * 16;
    short8 a12[4], arhu[2];
#pragma unroll
    for (int k0 = 0; k0 < 4; ++k0)
      a12[k0] = ldg8(A12 + (size_t)(sr + l15) * 128 + k0 * 32 + lg * 8);
#pragma unroll
    for (int kk = 0; kk < 2; ++kk)
      arhu[kk] = ldg8(rhU + (size_t)(sr + l15) * 64 + kk * 32 + lg * 8);
    if (rnd < 7) { STAGE(rnd + 1, (rnd + 1) & 1); VWAIT(4); }
    else         { VWAIT(0); }
    const char* H = (const char*)&hS[rnd & 1][w][0];

    float hv[4][4];
#pragma unroll
    for (int cf = 0; cf < 4; ++cf)
#pragma unroll
      for (int j = 0; j < 4; ++j) {
        int rr = lg * 4 + j;
        hv[cf][j] = *(const float*)(H + rr * 256 + ((cf * 64 + l15 * 4) ^ ((rr & 7) << 4)));
      }

    f32x4 aR[4] = {}, aZ[4] = {}, aC[4] = {};
#pragma unroll
    for (int k0 = 0; k0 < 4; ++k0) {
      const short8 a3 = (k0 < 2) ? a12[k0] : arhu[k0 - 2];
#pragma unroll
      for (int cf = 0; cf < 4; ++cf) {
        aR[cf] = mfma16(a12[k0], rd128s(sB1, cf * 16 + l15, k0 * 32 + lg * 8), aR[cf]);
        aZ[cf] = mfma16(a12[k0], rd128s(sB2, cf * 16 + l15, k0 * 32 + lg * 8), aZ[cf]);
        aC[cf] = mfma16(a3,      rd128s(sB3, cf * 16 + l15, k0 * 32 + lg * 8), aC[cf]);
      }
    }
#pragma unroll
    for (int cf = 0; cf < 4; ++cf) {
      const int cc = n0 + cf * 16 + l15;
#pragma unroll
      for (int j = 0; j < 4; ++j) {
        const size_t gi = (size_t)(sr + lg * 4 + j) * 1024 + cc;
        const float hvj = hv[cf][j];
        float rv = sigm_f(aR[cf][j] + hvj * d1_[cf] + br_[cf]);
        float zv = sigm_f(aZ[cf][j] + hvj * d2_[cf] + bz_[cf]);
        float cv = tanh_f(aC[cf][j] + rv * hvj * d3_[cf] + bu_[cf]);
        out[gi] = zv * hvj + (1.f - zv) * cv;
      }
    }
  }
}

extern "C" void kernel_launch(void* const* d_in, const int* in_sizes, int n_in,
                              void* d_out, int out_size, void* d_ws, size_t ws_size,
                              hipStream_t stream) {
  const float* x   = (const float*)d_in[0];
  const float* h   = (const float*)d_in[1];
  const float* W   = (const float*)d_in[2];
  const float* W1  = (const float*)d_in[3];
  const float* W2  = (const float*)d_in[4];
  const float* W3  = (const float*)d_in[5];
  const float* U   = (const float*)d_in[6];
  const float* U1  = (const float*)d_in[7];
  const float* U2  = (const float*)d_in[8];
  const float* U3  = (const float*)d_in[9];
  const float* u1d = (const float*)d_in[10];
  const float* u2d = (const float*)d_in[11];
  const float* u3d = (const float*)d_in[12];
  const float* bR  = (const float*)d_in[13];
  const float* bZ  = (const float*)d_in[14];
  const float* bU  = (const float*)d_in[15];
  short* ws  = (short*)d_ws;
  short* A12 = ws + WS_A12;
  short* rhU = ws + WS_RHU;

  prep_kernel<<<2048, 256, 0, stream>>>(W, W1, W2, W3, U, U1, U2, U3, ws);
  k1_a12<<<1024, 256, 0, stream>>>(x, h, ws, A12);
  k23_rhu<<<1024, 256, 0, stream>>>(h, u1d, bR, ws, A12, rhU);
  k4_out<<<1024, 256, 0, stream>>>(h, u1d, u2d, u3d, bR, bZ, bU, ws, A12, rhU, (float*)d_out);
}

// Round 20
// 209.620 us; speedup vs baseline: 1.1983x; 1.1983x over previous
//
#include <hip/hip_runtime.h>
#include <hip/hip_bf16.h>

// ---------------------------------------------------------------------------
// myGRUCell low-rank, R20 = R18 (best measured: 214.9 us) + k4 XCD swizzle.
//   k1 : A12 = [x@W | h@U] bf16.  Stationary weight matrix (128 KB LDS),
//        depth-8 register ring on x/h, VWAIT(14).  grid 512 x 512 thr.
//   k23: rhU (R7/R14 col-split).           [unchanged]
//   k4 : gates+out (R8/R14 stationary-B) + bijective XCD swizzle so the 16
//        ct-siblings sharing A12/rhU rows land on one XCD's L2.
// ws layout (shorts): Wt[64][1024] | Ut | P1t[1024][128] | P2t | P3t |
//                     A12[32768][128] | rhU[32768][64]
// ---------------------------------------------------------------------------

typedef __attribute__((ext_vector_type(8))) short short8;
typedef __attribute__((ext_vector_type(4))) float f32x4;
typedef __attribute__((ext_vector_type(4))) float f4;

#define WS_UT   65536
#define WS_P1T  131072
#define WS_P2T  262144
#define WS_P3T  393216
#define WS_A12  524288
#define WS_RHU  4718592

__device__ __forceinline__ short f2bf(float f) {
  unsigned u = __builtin_bit_cast(unsigned, f);
  u += 0x7FFFu + ((u >> 16) & 1u);          // round-nearest-even
  return (short)(u >> 16);
}
__device__ __forceinline__ short8 cvt8(f4 a, f4 b) {
  short8 r;
#pragma unroll
  for (int j = 0; j < 4; ++j) { r[j] = f2bf(a[j]); r[4 + j] = f2bf(b[j]); }
  return r;
}
__device__ __forceinline__ f32x4 mfma16(short8 a, short8 b, f32x4 c) {
  return __builtin_amdgcn_mfma_f32_16x16x32_bf16(a, b, c, 0, 0, 0);
}
__device__ __forceinline__ short8 ldg8(const short* p) {
  return *reinterpret_cast<const short8*>(p);
}
__device__ __forceinline__ f4 ldf4(const float* p) {
  return *reinterpret_cast<const f4*>(p);
}

// async 16B global->LDS
__device__ __forceinline__ void cp16(void* l, const void* g) {
  __builtin_amdgcn_global_load_lds(
      (const __attribute__((address_space(1))) void*)g,
      (__attribute__((address_space(3))) void*)l, 16, 0, 0);
}
#define VWAIT(N) do { asm volatile("s_waitcnt vmcnt(" #N ")" ::: "memory"); \
                      __builtin_amdgcn_sched_barrier(0); } while (0)

// [R][128]-short LDS tile, XOR-swizzled 16B granules
__device__ __forceinline__ short8 rd128s(const short* b, int row, int col) {
  return *reinterpret_cast<const short8*>(b + row * 128 + (col ^ ((row & 7) << 3)));
}
__device__ __forceinline__ void wr128s(short* b, int row, int col8, short8 v) {
  *reinterpret_cast<short8*>(b + row * 128 + (col8 ^ ((row & 7) << 3))) = v;
}
// [16][64]-short per-wave transpose buffer
__device__ __forceinline__ void wr64(short* b, int row, int col, short v) {
  b[row * 64 + (col ^ ((row & 7) << 3))] = v;
}
__device__ __forceinline__ short8 rd64(const short* b, int row, int col) {
  return *reinterpret_cast<const short8*>(b + row * 64 + (col ^ ((row & 7) << 3)));
}

#define LOG2E 1.4426950408889634f
__device__ __forceinline__ float sigm_f(float v) {
  return __builtin_amdgcn_rcpf(1.f + __builtin_amdgcn_exp2f(-v * LOG2E));
}
__device__ __forceinline__ float tanh_f(float v) {
  float t = __builtin_amdgcn_exp2f(v * (2.f * LOG2E));
  return 1.f - 2.f * __builtin_amdgcn_rcpf(t + 1.f);
}

// ---------------------------------------------------------------------------
__global__ void prep_kernel(const float* __restrict__ W,  const float* __restrict__ W1,
                            const float* __restrict__ W2, const float* __restrict__ W3,
                            const float* __restrict__ U,  const float* __restrict__ U1,
                            const float* __restrict__ U2, const float* __restrict__ U3,
                            short* __restrict__ ws) {
  int i = blockIdx.x * blockDim.x + threadIdx.x;
  float v;
  if (i < 65536) {
    int n = i >> 10, k = i & 1023;
    v = W[k * 64 + n];
  } else if (i < 131072) {
    int j = i - 65536;
    int n = j >> 10, k = j & 1023;
    v = U[k * 64 + n];
  } else {
    int j = i - 131072;
    int sel = j >> 17;
    int jj = j & 131071;
    int n = jj >> 7, k = jj & 127;
    const float* Wk = sel == 0 ? W1 : sel == 1 ? W2 : W3;
    const float* Uk = sel == 0 ? U1 : sel == 1 ? U2 : U3;
    v = (k < 64) ? Wk[k * 1024 + n] : Uk[(k - 64) * 1024 + n];
  }
  ws[i] = f2bf(v);
}

// ---------------------------------------------------------------------------
// k1 (R18): A12[:, m*64..] = (m? h : x) @ (m? U : W).
// Block = (m, 128-row chunk); 512 thr; weight matrix stationary in LDS.
// grid = 2 * 256 = 512 blocks.
// ---------------------------------------------------------------------------
__global__ __launch_bounds__(512, 1) void k1_a12(
    const float* __restrict__ x, const float* __restrict__ h,
    const short* __restrict__ ws, short* __restrict__ A12) {
  __shared__ __align__(16) short sW[64 * 1024];   // 128 KB, row-swizzled

  const int tid = threadIdx.x;
  const int w = tid >> 6, l = tid & 63, l15 = l & 15, lg = l >> 4;
  const int m  = blockIdx.x & 1;
  const int rc = blockIdx.x >> 1;          // 0..255
  const int sr = rc * 128 + w * 16;
  const float* src = m ? h : x;
  const short* Bt  = ws + m * WS_UT;

  // ---- stage weight matrix [64 rows][1024 k] bf16 -> LDS, swizzled source
#pragma unroll
  for (int rnd = 0; rnd < 16; ++rnd) {
    const int byte = rnd * 8192 + tid * 16;
    const int row  = byte >> 11;
    const int col  = byte & 2047;
    const int scol = col ^ ((row & 7) << 4);      // pre-swizzled source (rule 21)
    cp16((char*)sW + byte, (const char*)(Bt + row * 1024) + scol);
  }
  VWAIT(0);
  __syncthreads();

  auto rdW = [&](int row, int kcol) {
    const int byte = row * 2048 + ((kcol * 2) ^ ((row & 7) << 4));
    return *reinterpret_cast<const short8*>((const char*)sW + byte);
  };

  // ---- per-wave 16-row strip; 32-step K-loop; depth-8 register ring on A
  const float* xr = src + (size_t)(sr + l15) * 1024 + lg * 8;

  f4 ring[8][2];
#pragma unroll
  for (int i = 0; i < 8; ++i) {
    ring[i][0] = ldf4(xr + i * 32);
    ring[i][1] = ldf4(xr + i * 32 + 4);
  }

  f32x4 acc[4] = {};
#pragma unroll
  for (int c = 0; c < 32; ++c) {
    if (c < 25)      VWAIT(14);
    else if (c == 25) VWAIT(12);
    else if (c == 26) VWAIT(10);
    else if (c == 27) VWAIT(8);
    else if (c == 28) VWAIT(6);
    else if (c == 29) VWAIT(4);
    else if (c == 30) VWAIT(2);
    else              VWAIT(0);

    short8 av = cvt8(ring[c & 7][0], ring[c & 7][1]);
    const int kcol = c * 32 + lg * 8;
#pragma unroll
    for (int cf = 0; cf < 4; ++cf)
      acc[cf] = mfma16(av, rdW(cf * 16 + l15, kcol), acc[cf]);

    if (c < 24) {
      ring[c & 7][0] = ldf4(xr + (c + 8) * 32);
      ring[c & 7][1] = ldf4(xr + (c + 8) * 32 + 4);
    }
  }

#pragma unroll
  for (int cf = 0; cf < 4; ++cf)
#pragma unroll
    for (int j = 0; j < 4; ++j)
      A12[(size_t)(sr + lg * 4 + j) * 128 + m * 64 + cf * 16 + l15] = f2bf(acc[cf][j]);
}

// ---------------------------------------------------------------------------
// k23 (R7/R14, unchanged): rhU = (sigmoid(A12@P1 + h*U1d + bR) * h) @ U.
// ---------------------------------------------------------------------------
__global__ __launch_bounds__(256, 4) void k23_rhu(
    const float* __restrict__ h, const float* __restrict__ u1d,
    const float* __restrict__ biasR,
    const short* __restrict__ ws, const short* __restrict__ A12,
    short* __restrict__ rhU) {
  const short* Ut  = ws + WS_UT;
  const short* P1t = ws + WS_P1T;
  __shared__ __align__(16) short sT[4][2][16 * 64];
  __shared__ __align__(16) float sRed[2][2][16 * 64];

  const int tid = threadIdx.x;
  const int w   = tid >> 6, l = tid & 63, l15 = l & 15, lg = l >> 4;
  const int s   = w >> 1;
  const int ch  = w & 1;
  const int sr  = blockIdx.x * 32 + s * 16;

  short8 a12[4];
#pragma unroll
  for (int k0 = 0; k0 < 4; ++k0)
    a12[k0] = ldg8(A12 + (size_t)(sr + l15) * 128 + k0 * 32 + lg * 8);

  f32x4 accU[4] = {};
#pragma unroll 1
  for (int tt = 0; tt < 8; ++tt) {
    const int n0 = ch * 512 + tt * 64;

    float hv[4][4];
#pragma unroll
    for (int cf = 0; cf < 4; ++cf)
#pragma unroll
      for (int j = 0; j < 4; ++j)
        hv[cf][j] = h[(size_t)(sr + lg * 4 + j) * 1024 + n0 + cf * 16 + l15];

    f32x4 accR[4] = {};
#pragma unroll
    for (int k0 = 0; k0 < 4; ++k0)
#pragma unroll
      for (int cf = 0; cf < 4; ++cf)
        accR[cf] = mfma16(a12[k0],
            ldg8(P1t + (size_t)(n0 + cf * 16 + l15) * 128 + k0 * 32 + lg * 8),
            accR[cf]);

    short* sw = &sT[w][tt & 1][0];
#pragma unroll
    for (int cf = 0; cf < 4; ++cf) {
      const int cc = n0 + cf * 16 + l15;
      const float d1 = u1d[cc], b_r = biasR[cc];
#pragma unroll
      for (int j = 0; j < 4; ++j) {
        float rv = sigm_f(accR[cf][j] + hv[cf][j] * d1 + b_r);
        wr64(sw, lg * 4 + j, cf * 16 + l15, f2bf(rv * hv[cf][j]));
      }
    }
    // wave-coherent RAW through LDS (lgkmcnt only; R5-R19 proven)
    short8 arh0 = rd64(sw, l15, lg * 8);
    short8 arh1 = rd64(sw, l15, 32 + lg * 8);
#pragma unroll
    for (int cf = 0; cf < 4; ++cf)
      accU[cf] = mfma16(arh0,
          ldg8(Ut + (size_t)(cf * 16 + l15) * 1024 + n0 + lg * 8), accU[cf]);
#pragma unroll
    for (int cf = 0; cf < 4; ++cf)
      accU[cf] = mfma16(arh1,
          ldg8(Ut + (size_t)(cf * 16 + l15) * 1024 + n0 + 32 + lg * 8), accU[cf]);
  }

  {
    float* fT = &sRed[s][ch][0];
#pragma unroll
    for (int cf = 0; cf < 4; ++cf)
#pragma unroll
      for (int j = 0; j < 4; ++j) {
        int row = lg * 4 + j, col = cf * 16 + l15;
        fT[row * 64 + (col ^ ((row & 7) << 2))] = accU[cf][j];
      }
  }
  __syncthreads();
  if (ch == 0) {
    const float* f0 = &sRed[s][0][0];
    const float* f1 = &sRed[s][1][0];
#pragma unroll
    for (int cf = 0; cf < 4; ++cf)
#pragma unroll
      for (int j = 0; j < 4; ++j) {
        int row = lg * 4 + j, col = cf * 16 + l15;
        int idx = row * 64 + (col ^ ((row & 7) << 2));
        rhU[(size_t)(sr + row) * 64 + col] = f2bf(f0[idx] + f1[idx]);
      }
  }
}

// ---------------------------------------------------------------------------
// k4 (R8/R14 + XCD swizzle): out = z*h + (1-z)*tanh(pre_c).
// Bijective swizzle (grid 1024 % 8 == 0): ct-siblings (same rc, shared
// A12/rhU rows) land on one XCD's L2.
// ---------------------------------------------------------------------------
__global__ __launch_bounds__(256, 2) void k4_out(
    const float* __restrict__ h,
    const float* __restrict__ u1d, const float* __restrict__ u2d,
    const float* __restrict__ u3d,
    const float* __restrict__ biasR, const float* __restrict__ biasZ,
    const float* __restrict__ biasU,
    const short* __restrict__ ws, const short* __restrict__ A12,
    const short* __restrict__ rhU, float* __restrict__ out) {
  __shared__ __align__(16) short sB1[64 * 128], sB2[64 * 128], sB3[64 * 128];
  __shared__ __align__(16) float hS[2][4][16 * 64];

  const int tid = threadIdx.x;
  const int w = tid >> 6, l = tid & 63, l15 = l & 15, lg = l >> 4;
  const int lb = (blockIdx.x & 7) * 128 + (blockIdx.x >> 3);   // XCD swizzle
  const int ct = lb & 15, rc = lb >> 4;
  const int n0 = ct * 64;

#pragma unroll
  for (int mat = 0; mat < 3; ++mat) {
    const short* srcw = (mat == 0) ? (ws + WS_P1T) : (mat == 1) ? (ws + WS_P2T) : (ws + WS_P3T);
    short* dst = (mat == 0) ? sB1 : (mat == 1) ? sB2 : sB3;
#pragma unroll
    for (int i = 0; i < 4; ++i) {
      int id = tid + i * 256;
      int row = id >> 4, gc = id & 15;
      wr128s(dst, row, gc * 8, ldg8(srcw + (size_t)(n0 + row) * 128 + gc * 8));
    }
  }
  float d1_[4], d2_[4], d3_[4], br_[4], bz_[4], bu_[4];
#pragma unroll
  for (int cf = 0; cf < 4; ++cf) {
    const int cc = n0 + cf * 16 + l15;
    d1_[cf] = u1d[cc]; d2_[cf] = u2d[cc]; d3_[cf] = u3d[cc];
    br_[cf] = biasR[cc]; bz_[cf] = biasZ[cc]; bu_[cf] = biasU[cc];
  }
  __syncthreads();

  const int srow = l >> 4;
  const int slin = (l & 15) * 16;
  auto STAGE = [&](int rnd, int b) {
    const int sb = rc * 512 + rnd * 64 + w * 16;
#pragma unroll
    for (int i = 0; i < 4; ++i) {
      int r = i * 4 + srow;
      int kb = slin ^ ((r & 7) << 4);
      cp16((char*)&hS[b][w][0] + i * 1024,
           (const char*)(h + (size_t)(sb + r) * 1024 + n0) + kb);
    }
  };

  STAGE(0, 0);
#pragma unroll 1
  for (int rnd = 0; rnd < 8; ++rnd) {
    const int sr = rc * 512 + rnd * 64 + w * 16;
    short8 a12[4], arhu[2];
#pragma unroll
    for (int k0 = 0; k0 < 4; ++k0)
      a12[k0] = ldg8(A12 + (size_t)(sr + l15) * 128 + k0 * 32 + lg * 8);
#pragma unroll
    for (int kk = 0; kk < 2; ++kk)
      arhu[kk] = ldg8(rhU + (size_t)(sr + l15) * 64 + kk * 32 + lg * 8);
    if (rnd < 7) { STAGE(rnd + 1, (rnd + 1) & 1); VWAIT(4); }
    else         { VWAIT(0); }
    const char* H = (const char*)&hS[rnd & 1][w][0];

    float hv[4][4];
#pragma unroll
    for (int cf = 0; cf < 4; ++cf)
#pragma unroll
      for (int j = 0; j < 4; ++j) {
        int rr = lg * 4 + j;
        hv[cf][j] = *(const float*)(H + rr * 256 + ((cf * 64 + l15 * 4) ^ ((rr & 7) << 4)));
      }

    f32x4 aR[4] = {}, aZ[4] = {}, aC[4] = {};
#pragma unroll
    for (int k0 = 0; k0 < 4; ++k0) {
      const short8 a3 = (k0 < 2) ? a12[k0] : arhu[k0 - 2];
#pragma unroll
      for (int cf = 0; cf < 4; ++cf) {
        aR[cf] = mfma16(a12[k0], rd128s(sB1, cf * 16 + l15, k0 * 32 + lg * 8), aR[cf]);
        aZ[cf] = mfma16(a12[k0], rd128s(sB2, cf * 16 + l15, k0 * 32 + lg * 8), aZ[cf]);
        aC[cf] = mfma16(a3,      rd128s(sB3, cf * 16 + l15, k0 * 32 + lg * 8), aC[cf]);
      }
    }
#pragma unroll
    for (int cf = 0; cf < 4; ++cf) {
      const int cc = n0 + cf * 16 + l15;
#pragma unroll
      for (int j = 0; j < 4; ++j) {
        const size_t gi = (size_t)(sr + lg * 4 + j) * 1024 + cc;
        const float hvj = hv[cf][j];
        float rv = sigm_f(aR[cf][j] + hvj * d1_[cf] + br_[cf]);
        float zv = sigm_f(aZ[cf][j] + hvj * d2_[cf] + bz_[cf]);
        float cv = tanh_f(aC[cf][j] + rv * hvj * d3_[cf] + bu_[cf]);
        out[gi] = zv * hvj + (1.f - zv) * cv;
      }
    }
  }
}

extern "C" void kernel_launch(void* const* d_in, const int* in_sizes, int n_in,
                              void* d_out, int out_size, void* d_ws, size_t ws_size,
                              hipStream_t stream) {
  const float* x   = (const float*)d_in[0];
  const float* h   = (const float*)d_in[1];
  const float* W   = (const float*)d_in[2];
  const float* W1  = (const float*)d_in[3];
  const float* W2  = (const float*)d_in[4];
  const float* W3  = (const float*)d_in[5];
  const float* U   = (const float*)d_in[6];
  const float* U1  = (const float*)d_in[7];
  const float* U2  = (const float*)d_in[8];
  const float* U3  = (const float*)d_in[9];
  const float* u1d = (const float*)d_in[10];
  const float* u2d = (const float*)d_in[11];
  const float* u3d = (const float*)d_in[12];
  const float* bR  = (const float*)d_in[13];
  const float* bZ  = (const float*)d_in[14];
  const float* bU  = (const float*)d_in[15];
  short* ws  = (short*)d_ws;
  short* A12 = ws + WS_A12;
  short* rhU = ws + WS_RHU;

  prep_kernel<<<2048, 256, 0, stream>>>(W, W1, W2, W3, U, U1, U2, U3, ws);
  k1_a12<<<512, 512, 0, stream>>>(x, h, ws, A12);
  k23_rhu<<<1024, 256, 0, stream>>>(h, u1d, bR, ws, A12, rhU);
  k4_out<<<1024, 256, 0, stream>>>(h, u1d, u2d, u3d, bR, bZ, bU, ws, A12, rhU, (float*)d_out);
}